// Round 1
// baseline (15108.121 us; speedup 1.0000x reference)
//
#include <hip/hip_runtime.h>
#include <math.h>

// PGA: per-sample (2048) pipeline.
// Correctness strategy: reproduce LAPACK sgesdd Path 4t (16x128, jobz='A')
// discretely: sgelqf -> sorglq (Q cols 0..31) -> sgebd2 -> sbdsqr (ported,
// LAPACK>=3.10 slartg convention) -> sormbr(P^T). Then 10 PGA iterations in LDS.
//
// Scratch lives inside out1 (b=6 unit: L[256]+VT[256]; b=7 unit: Qcols[128][32]),
// overwritten by the final wa_full writes after being consumed (same block).

#define NTH 512

// ---------------- LAPACK helper ports (fp32 semantics) ----------------

__device__ __forceinline__ float slapy2f(float x, float y) {
  float xa = fabsf(x), ya = fabsf(y);
  float w = fmaxf(xa, ya), z = fminf(xa, ya);
  if (z == 0.f) return w;
  float q = z / w;
  return w * sqrtf(1.f + q * q);
}

// LAPACK >= 3.10 slartg sign convention: c = |f|/d >= 0, r = sign(f)*d.
__device__ __forceinline__ float slartgf(float f, float g, float& c, float& s) {
  if (g == 0.f) { c = 1.f; s = 0.f; return f; }
  if (f == 0.f) { c = 0.f; s = copysignf(1.f, g); return fabsf(g); }
  float d = sqrtf(f * f + g * g);
  c = fabsf(f) / d;
  float r = copysignf(d, f);
  s = g / r;
  return r;
}

__device__ void slas2f(float f, float g, float h, float& ssmin, float& ssmax) {
  float fa = fabsf(f), ga = fabsf(g), ha = fabsf(h);
  float fhmn = fminf(fa, ha), fhmx = fmaxf(fa, ha);
  if (fhmn == 0.f) {
    ssmin = 0.f;
    if (fhmx == 0.f) ssmax = ga;
    else {
      float mn = fminf(fhmx, ga), mx = fmaxf(fhmx, ga);
      float q = mn / mx;
      ssmax = mx * sqrtf(1.f + q * q);
    }
  } else {
    if (ga < fhmx) {
      float as = 1.f + fhmn / fhmx;
      float at = (fhmx - fhmn) / fhmx;
      float au = ga / fhmx; au = au * au;
      float c = 2.f / (sqrtf(as * as + au) + sqrtf(at * at + au));
      ssmin = fhmn * c;
      ssmax = fhmx / c;
    } else {
      float au = fhmx / ga;
      if (au == 0.f) {
        ssmin = (fhmn * fhmx) / ga;
        ssmax = ga;
      } else {
        float as = 1.f + fhmn / fhmx;
        float at = (fhmx - fhmn) / fhmx;
        float asu = as * au, atu = at * au;
        float c = 1.f / (sqrtf(1.f + asu * asu) + sqrtf(1.f + atu * atu));
        ssmin = (fhmn * c) * au;
        ssmin = ssmin + ssmin;
        ssmax = ga / (c + c);
      }
    }
  }
}

__device__ void slasv2f(float f, float g, float h, float& ssmin, float& ssmax,
                        float& snr, float& csr, float& snl, float& csl) {
  const float EPSF = 5.9604644775390625e-08f;
  float ft = f, fa = fabsf(f), ht = h, ha = fabsf(h);
  int pmax = 1;
  bool dswap = (ha > fa);
  if (dswap) {
    pmax = 3;
    float t = ft; ft = ht; ht = t;
    t = fa; fa = ha; ha = t;
  }
  float gt = g, ga = fabsf(g);
  float clt = 0.f, crt = 0.f, slt = 0.f, srt = 0.f;
  if (ga == 0.f) {
    ssmin = ha; ssmax = fa;
    clt = 1.f; crt = 1.f; slt = 0.f; srt = 0.f;
  } else {
    bool gasmal = true;
    if (ga > fa) {
      pmax = 2;
      if ((fa / ga) < EPSF) {
        gasmal = false;
        ssmax = ga;
        if (ha > 1.f) ssmin = fa / (ga / ha);
        else ssmin = (fa / ga) * ha;
        clt = 1.f; slt = ht / gt; srt = 1.f; crt = ft / gt;
      }
    }
    if (gasmal) {
      float dd = fa - ha;
      float l;
      if (dd == fa) l = 1.f; else l = dd / fa;
      float mm = gt / ft;
      float t = 2.f - l;
      float mm2 = mm * mm, tt = t * t;
      float sfac = sqrtf(tt + mm2);
      float r2;
      if (l == 0.f) r2 = fabsf(mm); else r2 = sqrtf(l * l + mm2);
      float a = 0.5f * (sfac + r2);
      ssmin = ha / a;
      ssmax = fa * a;
      if (mm2 == 0.f) {
        if (l == 0.f) t = copysignf(2.f, ft) * copysignf(1.f, gt);
        else t = gt / copysignf(dd, ft) + mm / t;
      } else {
        t = (mm / (sfac + t) + mm / (r2 + l)) * (1.f + a);
      }
      float l2 = sqrtf(t * t + 4.f);
      crt = 2.f / l2;
      srt = t / l2;
      clt = (crt + srt * mm) / a;
      slt = (ht / ft) * srt / a;
    }
  }
  if (dswap) { csl = srt; snl = crt; csr = slt; snr = clt; }
  else { csl = clt; snl = slt; csr = crt; snr = srt; }
  float tsign = 1.f;
  if (pmax == 1) tsign = copysignf(1.f, csr) * copysignf(1.f, csl) * copysignf(1.f, f);
  if (pmax == 2) tsign = copysignf(1.f, snr) * copysignf(1.f, csl) * copysignf(1.f, g);
  if (pmax == 3) tsign = copysignf(1.f, snr) * copysignf(1.f, snl) * copysignf(1.f, h);
  ssmax = copysignf(ssmax, tsign);
  ssmin = copysignf(ssmin, tsign * copysignf(1.f, f) * copysignf(1.f, h));
}

__device__ __forceinline__ void rot2(float* vt, int r1, int r2, float c, float s) {
#pragma unroll
  for (int j = 0; j < 16; ++j) {
    float x = vt[r1 * 16 + j], y = vt[r2 * 16 + j];
    vt[r1 * 16 + j] = c * x + s * y;
    vt[r2 * 16 + j] = c * y - s * x;
  }
}

// Faithful port of sbdsqr for n=16, upper bidiagonal, accumulating only VT
// (NCVT=16); control flow identical, U updates skipped (don't affect VT).
__device__ void bdsqr16(float* d, float* e, float* vt) {
  const float EPSF = 5.9604644775390625e-08f;   // 2^-24
  const float UNFLF = 1.1754943508222875e-38f;
  const int n = 16;
  const float tol = 10.f * EPSF;                // tolmul = max(10, eps^-1/8=8)
  float thresh;
  {
    float sminoa = fabsf(d[0]);
    if (sminoa != 0.f) {
      float mu = sminoa;
      for (int i = 1; i < n; ++i) {
        mu = fabsf(d[i]) * (mu / (mu + fabsf(e[i - 1])));
        sminoa = fminf(sminoa, mu);
        if (sminoa == 0.f) break;
      }
    }
    sminoa = sminoa / sqrtf((float)n);
    thresh = fmaxf(tol * sminoa, 6.f * n * (n * UNFLF));
  }
  int m = n, oldll = -1, oldm = -1, idir = 0, iter = 0;
  const int maxit = 6 * n * n;
  int passes = 0;
  while (m > 1 && passes++ < 4000) {
    if (iter > maxit) break;
    int ll;
    float smaxb;
    {
      smaxb = fabsf(d[m - 1]);
      float sminb = smaxb;
      int llf = 0, found = 0;
      for (int lll = 1; lll <= m - 1; ++lll) {
        int l1 = m - lll;
        float abss = fabsf(d[l1 - 1]);
        float abse = fabsf(e[l1 - 1]);
        if (abse <= thresh) { found = 1; llf = l1; break; }
        sminb = fminf(sminb, abss);
        smaxb = fmaxf(smaxb, fmaxf(abss, abse));
      }
      (void)sminb;
      if (found) {
        e[llf - 1] = 0.f;
        if (llf == m - 1) { m -= 1; continue; }
        ll = llf + 1;
      } else ll = 1;
    }
    if (ll == m - 1) {
      float sigmn, sigmx, sinr, cosr, sinl, cosl;
      slasv2f(d[m - 2], e[m - 2], d[m - 1], sigmn, sigmx, sinr, cosr, sinl, cosl);
      d[m - 2] = sigmx; e[m - 2] = 0.f; d[m - 1] = sigmn;
      rot2(vt, m - 2, m - 1, cosr, sinr);
      m -= 2;
      continue;
    }
    if (ll > oldm || m < oldll)
      idir = (fabsf(d[ll - 1]) >= fabsf(d[m - 1])) ? 1 : 2;
    float sminl = 0.f;
    int conv = 0;
    if (idir == 1) {
      if (fabsf(e[m - 2]) <= tol * fabsf(d[m - 1])) { e[m - 2] = 0.f; continue; }
      float mu = fabsf(d[ll - 1]); sminl = mu;
      for (int lll = ll; lll <= m - 1; ++lll) {
        if (fabsf(e[lll - 1]) <= tol * mu) { e[lll - 1] = 0.f; conv = 1; break; }
        mu = fabsf(d[lll]) * (mu / (mu + fabsf(e[lll - 1])));
        sminl = fminf(sminl, mu);
      }
    } else {
      if (fabsf(e[ll - 1]) <= tol * fabsf(d[ll - 1])) { e[ll - 1] = 0.f; continue; }
      float mu = fabsf(d[m - 1]); sminl = mu;
      for (int lll = m - 1; lll >= ll; --lll) {
        if (fabsf(e[lll - 1]) <= tol * mu) { e[lll - 1] = 0.f; conv = 1; break; }
        mu = fabsf(d[lll - 1]) * (mu / (mu + fabsf(e[lll - 1])));
        sminl = fminf(sminl, mu);
      }
    }
    if (conv) continue;
    oldll = ll; oldm = m;
    float shift = 0.f;
    if (!((float)n * tol * (sminl / smaxb) <= fmaxf(EPSF, 0.01f * tol))) {
      float sll, rr;
      if (idir == 1) { sll = fabsf(d[ll - 1]); slas2f(d[m - 2], e[m - 2], d[m - 1], shift, rr); }
      else           { sll = fabsf(d[m - 1]);  slas2f(d[ll - 1], e[ll - 1], d[ll], shift, rr); }
      if (sll > 0.f) { float q = shift / sll; if (q * q < EPSF) shift = 0.f; }
    }
    iter += m - ll;
    if (shift == 0.f) {
      if (idir == 1) {
        float cs = 1.f, oldcs = 1.f, sn = 0.f, oldsn = 0.f;
        for (int i = ll; i <= m - 1; ++i) {
          float r = slartgf(d[i - 1] * cs, e[i - 1], cs, sn);
          if (i > ll) e[i - 2] = oldsn * r;
          d[i - 1] = slartgf(oldcs * r, d[i] * sn, oldcs, oldsn);
          rot2(vt, i - 1, i, cs, sn);
        }
        float h2 = d[m - 1] * cs;
        d[m - 1] = h2 * oldcs;
        e[m - 2] = h2 * oldsn;
        if (fabsf(e[m - 2]) <= thresh) e[m - 2] = 0.f;
      } else {
        float cs = 1.f, oldcs = 1.f, sn = 0.f, oldsn = 0.f;
        for (int i = m; i >= ll + 1; --i) {
          float r = slartgf(d[i - 1] * cs, e[i - 2], cs, sn);
          if (i < m) e[i - 1] = oldsn * r;
          d[i - 1] = slartgf(oldcs * r, d[i - 2] * sn, oldcs, oldsn);
          rot2(vt, i - 2, i - 1, oldcs, -oldsn);
        }
        float h2 = d[ll - 1] * cs;
        d[ll - 1] = h2 * oldcs;
        e[ll - 1] = h2 * oldsn;
        if (fabsf(e[ll - 1]) <= thresh) e[ll - 1] = 0.f;
      }
    } else {
      if (idir == 1) {
        float f = (fabsf(d[ll - 1]) - shift) * (copysignf(1.f, d[ll - 1]) + shift / d[ll - 1]);
        float g = e[ll - 1];
        for (int i = ll; i <= m - 1; ++i) {
          float cosr, sinr, cosl, sinl;
          float r = slartgf(f, g, cosr, sinr);
          if (i > ll) e[i - 2] = r;
          f = cosr * d[i - 1] + sinr * e[i - 1];
          e[i - 1] = cosr * e[i - 1] - sinr * d[i - 1];
          g = sinr * d[i];
          d[i] = cosr * d[i];
          r = slartgf(f, g, cosl, sinl);
          d[i - 1] = r;
          f = cosl * e[i - 1] + sinl * d[i];
          d[i] = cosl * d[i] - sinl * e[i - 1];
          if (i < m - 1) {
            g = sinl * e[i];
            e[i] = cosl * e[i];
          }
          rot2(vt, i - 1, i, cosr, sinr);
        }
        e[m - 2] = f;
        if (fabsf(e[m - 2]) <= thresh) e[m - 2] = 0.f;
      } else {
        float f = (fabsf(d[m - 1]) - shift) * (copysignf(1.f, d[m - 1]) + shift / d[m - 1]);
        float g = e[m - 2];
        for (int i = m; i >= ll + 1; --i) {
          float cosr, sinr, cosl, sinl;
          float r = slartgf(f, g, cosr, sinr);
          if (i < m) e[i - 1] = r;
          f = cosr * d[i - 1] + sinr * e[i - 2];
          e[i - 2] = cosr * e[i - 2] - sinr * d[i - 1];
          g = sinr * d[i - 2];
          d[i - 2] = cosr * d[i - 2];
          r = slartgf(f, g, cosl, sinl);
          d[i - 1] = r;
          f = cosl * e[i - 2] + sinl * d[i - 2];
          d[i - 2] = cosl * d[i - 2] - sinl * e[i - 2];
          if (i > ll + 1) {
            g = sinl * e[i - 3];
            e[i - 3] = cosl * e[i - 3];
          }
          rot2(vt, i - 2, i - 1, cosl, -sinl);
        }
        e[ll - 1] = f;
        if (fabsf(e[ll - 1]) <= thresh) e[ll - 1] = 0.f;
      }
    }
  }
  // make singular values positive (flip VT row)
  for (int i = 0; i < n; ++i) {
    if (d[i] < 0.f) {
      d[i] = -d[i];
#pragma unroll
      for (int j = 0; j < 16; ++j) vt[i * 16 + j] = -vt[i * 16 + j];
    }
  }
  // sort decreasing, LAPACK's selection (<= -> last smallest)
  for (int i = 1; i <= n - 1; ++i) {
    int isub = 1;
    float smin = d[0];
    for (int j = 2; j <= n + 1 - i; ++j)
      if (d[j - 1] <= smin) { isub = j; smin = d[j - 1]; }
    if (isub != n + 1 - i) {
      d[isub - 1] = d[n - i]; d[n - i] = smin;
      for (int j = 0; j < 16; ++j) {
        float t = vt[(isub - 1) * 16 + j];
        vt[(isub - 1) * 16 + j] = vt[(n - i) * 16 + j];
        vt[(n - i) * 16 + j] = t;
      }
    }
  }
}

// ---------------- K2: mean + LQ + Q columns ----------------

__global__ __launch_bounds__(64) void k_lq(const float* __restrict__ h,
                                           float* __restrict__ Lq,
                                           float* __restrict__ Qc) {
  __shared__ float E[16][129];
  __shared__ float q[32][129];
  __shared__ float tauv[16];
  __shared__ float part4[16][4];
  __shared__ float red[64];
  __shared__ float sh_scal;
  __shared__ int sh_do;
  const int s = blockIdx.x;
  const int tid = threadIdx.x;

  // E = mean over b (sequential order, like np.add.reduce axis 0), /8 exact
  for (int o = tid; o < 16 * 128; o += 64) {
    int nrow = o >> 7, k = o & 127;
    size_t base = (size_t)s * 2048 + o;
    float acc = 0.f;
    for (int b = 0; b < 8; ++b) acc += h[base + (size_t)b * 4194304];
    E[nrow][k] = acc * 0.125f;
    (void)nrow; (void)k;
  }
  __syncthreads();

  for (int i = 0; i < 16; ++i) {
    // ||E[i][i+1:]||^2
    float p = 0.f;
    for (int j = i + 1 + tid; j < 128; j += 64) { float v = E[i][j]; p += v * v; }
    red[tid] = p;
    __syncthreads();
    for (int off = 32; off >= 1; off >>= 1) {
      if (tid < off) red[tid] += red[tid + off];
      __syncthreads();
    }
    if (tid == 0) {
      float alpha = E[i][i];
      if (red[0] == 0.f) {
        tauv[i] = 0.f; sh_scal = 0.f; sh_do = 0;
      } else {
        float xnorm = sqrtf(red[0]);
        float beta = -copysignf(slapy2f(alpha, xnorm), alpha);
        tauv[i] = (beta - alpha) / beta;
        sh_scal = 1.f / (alpha - beta);
        sh_do = 1;
        E[i][i] = beta;
      }
    }
    __syncthreads();
    if (sh_do) {
      float sc = sh_scal;
      for (int j = i + 1 + tid; j < 128; j += 64) E[i][j] *= sc;
    }
    __syncthreads();
    // apply H(i) from the right to rows i+1..15
    {
      int r = tid >> 2, seg = tid & 3;
      float pp = 0.f;
      if (r > i) {
        for (int j = i + 1 + seg; j < 128; j += 4) pp += E[r][j] * E[i][j];
      }
      part4[r][seg] = pp;
      __syncthreads();
      if (r > i) {
        float w = E[r][i] + part4[r][0] + part4[r][1] + part4[r][2] + part4[r][3];
        float tw = tauv[i] * w;
        if (seg == 0) E[r][i] -= tw;
        for (int j = i + 1 + seg; j < 128; j += 4) E[r][j] -= tw * E[i][j];
      }
      __syncthreads();
    }
  }

  // L (lower incl diag), zeros above
  for (int o = tid; o < 256; o += 64) {
    int r = o >> 4, c = o & 15;
    Lq[(size_t)s * 4096 + o] = (c <= r) ? E[r][c] : 0.f;
  }

  // Q = H(16)...H(1); columns 0..31: apply H(1) first
  if (tid < 32) {
    int c = tid;
    for (int j = 0; j < 128; ++j) q[c][j] = (j == c) ? 1.f : 0.f;
    for (int i = 0; i < 16; ++i) {
      float dot = q[c][i];
      for (int j = i + 1; j < 128; ++j) dot += E[i][j] * q[c][j];
      float td = tauv[i] * dot;
      q[c][i] -= td;
      for (int j = i + 1; j < 128; ++j) q[c][j] -= td * E[i][j];
    }
  }
  __syncthreads();
  for (int o = tid; o < 4096; o += 64) {
    int jrow = o >> 5, c = o & 31;
    Qc[(size_t)s * 4096 + o] = q[c][jrow];
  }
}

// ---------------- K3: 16x16 SVD (gebd2 + bdsqr + P^T) ----------------

__global__ __launch_bounds__(32) void k_svd16(float* __restrict__ LqVT) {
  __shared__ float lds[32][567];
  const int tid = threadIdx.x;
  const int sid = blockIdx.x * 32 + tid;
  float* aw = &lds[tid][0];     // 16x16 work (reflectors)
  float* vt = &lds[tid][256];   // 16x16 VT
  float* d = &lds[tid][512];
  float* e = &lds[tid][528];
  float* tp = &lds[tid][544];
  const float* Lsrc = LqVT + (size_t)sid * 4096;
  for (int o = 0; o < 256; ++o) aw[o] = Lsrc[o];

  // sgebd2 (m=n=16): column reflector H(i), row reflector G(i)
  for (int i = 0; i < 16; ++i) {
    {
      float alpha = aw[i * 16 + i];
      float ssq = 0.f;
      for (int r = i + 1; r < 16; ++r) { float v = aw[r * 16 + i]; ssq += v * v; }
      float tq;
      if (ssq == 0.f) { tq = 0.f; d[i] = alpha; }
      else {
        float xnorm = sqrtf(ssq);
        float beta = -copysignf(slapy2f(alpha, xnorm), alpha);
        tq = (beta - alpha) / beta;
        float sc = 1.f / (alpha - beta);
        for (int r = i + 1; r < 16; ++r) aw[r * 16 + i] *= sc;
        d[i] = beta;
      }
      if (tq != 0.f) {
        for (int c = i + 1; c < 16; ++c) {
          float w = aw[i * 16 + c];
          for (int r = i + 1; r < 16; ++r) w += aw[r * 16 + i] * aw[r * 16 + c];
          w *= tq;
          aw[i * 16 + c] -= w;
          for (int r = i + 1; r < 16; ++r) aw[r * 16 + c] -= w * aw[r * 16 + i];
        }
      }
    }
    if (i < 15) {
      float alpha = aw[i * 16 + i + 1];
      float ssq = 0.f;
      for (int c = i + 2; c < 16; ++c) { float v = aw[i * 16 + c]; ssq += v * v; }
      float tpv;
      if (ssq == 0.f) { tpv = 0.f; e[i] = alpha; }
      else {
        float xnorm = sqrtf(ssq);
        float beta = -copysignf(slapy2f(alpha, xnorm), alpha);
        tpv = (beta - alpha) / beta;
        float sc = 1.f / (alpha - beta);
        for (int c = i + 2; c < 16; ++c) aw[i * 16 + c] *= sc;
        e[i] = beta;
      }
      tp[i] = tpv;
      if (tpv != 0.f) {
        for (int r = i + 1; r < 16; ++r) {
          float w = aw[r * 16 + i + 1];
          for (int c = i + 2; c < 16; ++c) w += aw[r * 16 + c] * aw[i * 16 + c];
          w *= tpv;
          aw[r * 16 + i + 1] -= w;
          for (int c = i + 2; c < 16; ++c) aw[r * 16 + c] -= w * aw[i * 16 + c];
        }
      }
    } else {
      tp[i] = 0.f;
    }
  }

  // VT = I, QR iteration, then VT := VT * P^T (apply G(15) first)
  for (int o = 0; o < 256; ++o) vt[o] = 0.f;
  for (int i = 0; i < 16; ++i) vt[i * 16 + i] = 1.f;
  bdsqr16(d, e, vt);
  for (int i = 14; i >= 0; --i) {
    float tpv = tp[i];
    if (tpv != 0.f) {
      for (int r = 0; r < 16; ++r) {
        float w = vt[r * 16 + i + 1];
        for (int c = i + 2; c < 16; ++c) w += vt[r * 16 + c] * aw[i * 16 + c];
        w *= tpv;
        vt[r * 16 + i + 1] -= w;
        for (int c = i + 2; c < 16; ++c) vt[r * 16 + c] -= w * aw[i * 16 + c];
      }
    }
  }
  float* Vdst = LqVT + (size_t)sid * 4096 + 256;
  for (int o = 0; o < 256; ++o) Vdst[o] = vt[o];
}

// ---------------- K5: main PGA iterations ----------------

__global__ __launch_bounds__(512) void k_main(
    const float* __restrict__ h, const float* __restrict__ hyp,
    const float* __restrict__ wd_init, const int* __restrict__ niter_p,
    float* __restrict__ out0, float* __restrict__ out1, float* __restrict__ out2,
    const float* __restrict__ LqVT, const float* __restrict__ Qc) {
  __shared__ float h_s[8][16][129];   // 66 KB
  __shared__ float wa_s[128][33];     // 16.5 KB
  __shared__ float wd_s[8][32][17];   // 17 KB
  __shared__ float T_s[8][16][33];    // 16.5 KB
  __shared__ float A_s[8][16][17];    // 8.5 KB
  __shared__ float S_s[8][16][17];    // 8.5 KB
  __shared__ float G_s[8][16][17];    // 8.5 KB
  __shared__ float M32[32][33];       // 4.1 KB
  __shared__ float red_s[512];
  __shared__ float ldet_s[8];
  __shared__ float sca_sh;
  __shared__ float hyp_sh[96];

  const int s = blockIdx.x;
  const int tid = threadIdx.x;
  int niter = *niter_p;
  niter = (niter < 0) ? 0 : ((niter > 10) ? 10 : niter);

  // ---- prologue ----
  for (int o = tid; o < 8 * 2048; o += NTH) {
    int b = o >> 11, rem = o & 2047;
    h_s[b][rem >> 7][rem & 127] = h[(size_t)b * 4194304 + (size_t)s * 2048 + rem];
  }
  for (int o = tid; o < 90; o += NTH) hyp_sh[o] = hyp[o];
  for (int o = tid; o < 256; o += NTH)
    A_s[0][o >> 4][o & 15] = LqVT[(size_t)s * 4096 + 256 + o];  // VT_L
  for (int o = tid; o < 4096; o += NTH) {
    int mrow = o >> 5, l = o & 31;
    float v = Qc[(size_t)s * 4096 + o];
    if (mrow >= 16) wa_s[mrow][l] = v;    // wa rows 16..127 = Q rows
    else T_s[0][mrow][l] = v;             // Q top 16 rows
  }
  for (int o = tid; o < 4096; o += NTH) {
    int b = o >> 9, rem = o & 511;
    wd_s[b][rem >> 4][rem & 15] = wd_init[(size_t)b * 1048576 + (size_t)s * 512 + rem];
  }
  __syncthreads();
  for (int o = tid; o < 512; o += NTH) {  // wa rows 0..15 = VT_L @ Qtop
    int mrow = o >> 5, l = o & 31;
    float acc = 0.f;
    for (int k = 0; k < 16; ++k) acc += A_s[0][mrow][k] * T_s[0][k][l];
    wa_s[mrow][l] = acc;
  }
  __syncthreads();

  // power scale: p = tr((wa^T wa)(sum_b wd wd^T)); scale = sqrt(128/p)
  auto power_scale = [&](int which) {  // 0: scale wd, 1: scale wa
    for (int o = tid; o < 1024; o += NTH) {
      int l = o >> 5, lp = o & 31;
      float acc = 0.f;
      for (int b = 0; b < 8; ++b)
#pragma unroll 4
        for (int nn = 0; nn < 16; ++nn) acc += wd_s[b][l][nn] * wd_s[b][lp][nn];
      M32[l][lp] = acc;
    }
    __syncthreads();
    float part = 0.f;
    for (int o = tid; o < 1024; o += NTH) {
      int i2 = o >> 5, j2 = o & 31;
      float acc = 0.f;
      for (int k = 0; k < 128; ++k) acc += wa_s[k][i2] * wa_s[k][j2];
      part += acc * M32[j2][i2];
    }
    red_s[tid] = part;
    __syncthreads();
    for (int off = 256; off >= 1; off >>= 1) {
      if (tid < off) red_s[tid] += red_s[tid + off];
      __syncthreads();
    }
    if (tid == 0) sca_sh = sqrtf(128.f / red_s[0]);
    __syncthreads();
    float sc = sca_sh;
    if (which == 1) {
      for (int o = tid; o < 4096; o += NTH) wa_s[o >> 5][o & 31] *= sc;
    } else {
      for (int o = tid; o < 4096; o += NTH) {
        int b = o >> 9, rem = o & 511;
        wd_s[b][rem >> 4][rem & 15] *= sc;
      }
    }
    __syncthreads();
  };

  auto matmul_T = [&]() {  // T_s = h_s @ wa_s  (per b: 16x128 @ 128x32)
    int pair = tid >> 2, lseg = tid & 3;
    int b = pair >> 4, nrow = pair & 15, l0 = lseg * 8;
    float acc[8];
#pragma unroll
    for (int li = 0; li < 8; ++li) acc[li] = 0.f;
    for (int k = 0; k < 128; ++k) {
      float hv = h_s[b][nrow][k];
#pragma unroll
      for (int li = 0; li < 8; ++li) acc[li] += hv * wa_s[k][l0 + li];
    }
#pragma unroll
    for (int li = 0; li < 8; ++li) T_s[b][nrow][l0 + li] = acc[li];
    __syncthreads();
  };

  auto compute_A = [&]() {  // A_s = T_s @ wd_s
    for (int o = tid; o < 2048; o += NTH) {
      int b = o >> 8, rem = o & 255, i2 = rem >> 4, j2 = rem & 15;
      float acc = 0.f;
#pragma unroll 8
      for (int l = 0; l < 32; ++l) acc += T_s[b][i2][l] * wd_s[b][l][j2];
      A_s[b][i2][j2] = acc;
    }
    __syncthreads();
  };

  auto compute_S = [&](int withG) {  // S_s = I + A A^T (+ G = I)
    for (int o = tid; o < 2048; o += NTH) {
      int b = o >> 8, rem = o & 255, i2 = rem >> 4, j2 = rem & 15;
      float dlt = (i2 == j2) ? 1.f : 0.f;
      if (withG) G_s[b][i2][j2] = dlt;
      float acc = 0.f;
#pragma unroll 4
      for (int k = 0; k < 16; ++k) acc += A_s[b][i2][k] * A_s[b][j2][k];
      S_s[b][i2][j2] = dlt + acc;
    }
    __syncthreads();
  };

  auto invert_S = [&]() {  // G = S^-1 via no-pivot Gauss-Jordan (S SPD)
    for (int k = 0; k < 16; ++k) {
      if (tid < 128) {
        int b = tid >> 4, r = tid & 15;
        if (r == k) {
          float ip = 1.f / S_s[b][k][k];
#pragma unroll 4
          for (int c = 0; c < 16; ++c) { S_s[b][k][c] *= ip; G_s[b][k][c] *= ip; }
        }
      }
      __syncthreads();
      if (tid < 128) {
        int b = tid >> 4, r = tid & 15;
        if (r != k) {
          float fmul = S_s[b][r][k];
#pragma unroll 4
          for (int c = 0; c < 16; ++c) {
            S_s[b][r][c] -= fmul * S_s[b][k][c];
            G_s[b][r][c] -= fmul * G_s[b][k][c];
          }
        }
      }
      __syncthreads();
    }
    // X = G @ A -> S_s  (GinvT = G: inverse of symmetric is symmetric)
    for (int o = tid; o < 2048; o += NTH) {
      int b = o >> 8, rem = o & 255, i2 = rem >> 4, j2 = rem & 15;
      float acc = 0.f;
#pragma unroll 4
      for (int k = 0; k < 16; ++k) acc += G_s[b][i2][k] * A_s[b][k][j2];
      S_s[b][i2][j2] = acc;
    }
    __syncthreads();
  };

  power_scale(0);  // wd = scale0 * wd_init

  for (int it = 0; it < niter; ++it) {
    float mu0 = hyp_sh[it * 9];

    matmul_T();                // T1 = h @ wa
    compute_A();               // A = T1 @ wd
    compute_S(1);
    invert_S();                // S_s = GinvT @ A
    // Y = X @ wd^T -> T_s
    for (int o = tid; o < 4096; o += NTH) {
      int b = o >> 9, rem = o & 511, i2 = rem >> 5, l = rem & 31;
      float acc = 0.f;
#pragma unroll 4
      for (int j2 = 0; j2 < 16; ++j2) acc += S_s[b][i2][j2] * wd_s[b][l][j2];
      T_s[b][i2][l] = acc;
    }
    __syncthreads();
    // wa += mu0 * mean_b(h^T Y)
    {
      int mrow = tid >> 2, lseg = tid & 3, l0 = lseg * 8;
      float acc[8];
#pragma unroll
      for (int li = 0; li < 8; ++li) acc[li] = 0.f;
      for (int b = 0; b < 8; ++b)
        for (int nn = 0; nn < 16; ++nn) {
          float hv = h_s[b][nn][mrow];
#pragma unroll
          for (int li = 0; li < 8; ++li) acc[li] += hv * T_s[b][nn][l0 + li];
        }
#pragma unroll
      for (int li = 0; li < 8; ++li) wa_s[mrow][l0 + li] += mu0 * (acc[li] * 0.125f);
    }
    __syncthreads();
    power_scale(1);            // wa_new

    matmul_T();                // T2 = h @ wa_new
    compute_A();               // A2
    compute_S(1);
    invert_S();                // S_s = G2invT @ A2
    // wd += mu_b * (T2^T X2)/8
    for (int o = tid; o < 4096; o += NTH) {
      int b = o >> 9, rem = o & 511, l = rem >> 4, j2 = rem & 15;
      float acc = 0.f;
#pragma unroll 4
      for (int k = 0; k < 16; ++k) acc += T_s[b][k][l] * S_s[b][k][j2];
      wd_s[b][l][j2] += hyp_sh[it * 9 + 1 + b] * (acc * 0.125f);
    }
    __syncthreads();
    power_scale(0);            // wd_new

    compute_A();               // A3 = T2 @ wd_new
    compute_S(0);              // S3 = I + A3 A3^T
    if (tid < 8) ldet_s[tid] = 0.f;
    __syncthreads();
    for (int k = 0; k < 16; ++k) {
      if (tid < 128) {
        int b = tid >> 4, r = tid & 15;
        if (r == k) ldet_s[b] += logf(S_s[b][k][k]);
        if (r > k) {
          float fmul = S_s[b][r][k] / S_s[b][k][k];
          for (int c = k + 1; c < 16; ++c) S_s[b][r][c] -= fmul * S_s[b][k][c];
        }
      }
      __syncthreads();
    }
    if (tid == 0) {
      float acc = 0.f;
      for (int b = 0; b < 8; ++b) acc += ldet_s[b];
      out0[(size_t)s * 10 + it] = acc * 0.125f;
    }
    __syncthreads();
  }

  // ---- epilogue ----
  for (int o = tid; o < 4096; o += NTH) {
    float v = wa_s[o >> 5][o & 31];
#pragma unroll
    for (int b = 0; b < 8; ++b)
      out1[(size_t)b * 8388608 + (size_t)s * 4096 + o] = v;
  }
  for (int o = tid; o < 4096; o += NTH) {
    int b = o >> 9, rem = o & 511;
    out2[(size_t)b * 1048576 + (size_t)s * 512 + rem] = wd_s[b][rem >> 4][rem & 15];
  }
  for (int it2 = niter + tid; it2 < 10; it2 += NTH) out0[(size_t)s * 10 + it2] = 0.f;
}

// ---------------- host ----------------

extern "C" void kernel_launch(void* const* d_in, const int* in_sizes, int n_in,
                              void* d_out, int out_size, void* d_ws, size_t ws_size,
                              hipStream_t stream) {
  (void)in_sizes; (void)n_in; (void)out_size; (void)d_ws; (void)ws_size;
  const float* h = (const float*)d_in[0];
  const float* hyp = (const float*)d_in[1];
  const float* wd_init = (const float*)d_in[2];
  const int* niter_p = (const int*)d_in[3];
  float* out = (float*)d_out;
  float* out0 = out;                                  // (2048,10)
  float* out1 = out + 20480;                          // (8,2048,128,32)
  float* out2 = out1 + (size_t)67108864;              // (8,2048,32,16)
  float* Lq = out1 + (size_t)6 * 2048 * 4096;         // per s: L[256], VT[256]
  float* Qc = out1 + (size_t)7 * 2048 * 4096;         // per s: Q[:, :32] as [128][32]

  hipLaunchKernelGGL(k_lq, dim3(2048), dim3(64), 0, stream, h, Lq, Qc);
  hipLaunchKernelGGL(k_svd16, dim3(64), dim3(32), 0, stream, Lq);
  hipLaunchKernelGGL(k_main, dim3(2048), dim3(512), 0, stream,
                     h, hyp, wd_init, niter_p, out0, out1, out2, Lq, Qc);
}